// Round 5
// baseline (150.794 us; speedup 1.0000x reference)
//
#include <hip/hip_runtime.h>

#define DIM 1024
#define SEQ 2048
#define BATCH 2
#define NHEADS 16
#define HD 64
#define ROWS (BATCH * SEQ) // 4096

typedef __bf16 bf16x8 __attribute__((ext_vector_type(8)));
typedef __bf16 bf16x4 __attribute__((ext_vector_type(4)));
typedef float f32x4 __attribute__((ext_vector_type(4)));
typedef float f32x16 __attribute__((ext_vector_type(16)));
typedef unsigned u32x4 __attribute__((ext_vector_type(4)));

__device__ __forceinline__ f32x4 f4zero() {
    f32x4 z = {0.f, 0.f, 0.f, 0.f};
    return z;
}

__device__ __forceinline__ unsigned cvtpk(float lo, float hi) {
    unsigned r;
    asm("v_cvt_pk_bf16_f32 %0, %1, %2" : "=v"(r) : "v"(lo), "v"(hi));
    return r;
}

__device__ __forceinline__ void pl32swap(unsigned& a, unsigned& b) {
    asm volatile("v_permlane32_swap_b32 %0, %1" : "+v"(a), "+v"(b));
}

#define GLOAD_LDS16(g, l)                                                                  \
    __builtin_amdgcn_global_load_lds((const __attribute__((address_space(1))) void*)(g),   \
                                     (__attribute__((address_space(3))) void*)(l), 16, 0, 0)

// ---------------- RMSNorm -> bf16 ----------------
__global__ __launch_bounds__(256) void rmsnorm_bf16(const float* __restrict__ x,
                                                    const float* __restrict__ w,
                                                    __bf16* __restrict__ xn) {
    int row = blockIdx.x;
    int t = threadIdx.x;
    float4 v = ((const float4*)(x + (size_t)row * DIM))[t];
    float ss = v.x * v.x + v.y * v.y + v.z * v.z + v.w * v.w;
#pragma unroll
    for (int off = 1; off < 64; off <<= 1) ss += __shfl_xor(ss, off);
    __shared__ float red[4];
    if ((t & 63) == 0) red[t >> 6] = ss;
    __syncthreads();
    ss = red[0] + red[1] + red[2] + red[3];
    float scale = rsqrtf(ss * (1.0f / DIM) + 1e-5f);
    float4 wv = ((const float4*)w)[t];
    bf16x4 o;
    o[0] = (__bf16)(v.x * scale * wv.x);
    o[1] = (__bf16)(v.y * scale * wv.y);
    o[2] = (__bf16)(v.z * scale * wv.z);
    o[3] = (__bf16)(v.w * scale * wv.w);
    *(bf16x4*)(xn + (size_t)row * DIM + t * 4) = o;
}

// ---------------- Weight convert + transpose: W[k][n] f32 -> Wt[n][k] bf16 ----------------
__global__ __launch_bounds__(256) void wcvt_kernel(const float* __restrict__ Wq,
                                                   const float* __restrict__ Wk,
                                                   const float* __restrict__ Wv,
                                                   const float* __restrict__ Wo,
                                                   __bf16* tq, __bf16* tk, __bf16* tv, __bf16* to_) {
    int z = blockIdx.z;
    const float* W = z == 0 ? Wq : z == 1 ? Wk : z == 2 ? Wv : Wo;
    __bf16* T = z == 0 ? tq : z == 1 ? tk : z == 2 ? tv : to_;
    __shared__ float tile[32][33];
    int n0 = blockIdx.x * 32, k0 = blockIdx.y * 32;
    int tx = threadIdx.x & 31, ty = threadIdx.x >> 5;
#pragma unroll
    for (int j = 0; j < 32; j += 8) tile[ty + j][tx] = W[(size_t)(k0 + ty + j) * DIM + n0 + tx];
    __syncthreads();
#pragma unroll
    for (int j = 0; j < 32; j += 8)
        T[(size_t)(n0 + ty + j) * DIM + k0 + tx] = (__bf16)tile[tx][ty + j];
}

// ---------------- RoPE table ----------------
__global__ __launch_bounds__(256) void rope_table_kernel(float* __restrict__ cosT,
                                                         float* __restrict__ sinT) {
    int idx = blockIdx.x * 256 + threadIdx.x; // SEQ*32
    int s = idx >> 5, i = idx & 31;
    float e = (2.0f * (float)i) / 64.0f;
    float theta = 1.0f / powf(1000000.0f, e);
    float ang = (float)s * theta;
    cosT[idx] = cosf(ang);
    sinT[idx] = sinf(ang);
}

// ---------------- MFMA GEMM core (m97-style), acc left in registers ----------------
__device__ __forceinline__ void gemm_core(const __bf16* __restrict__ A,
                                          const __bf16* __restrict__ Bt,
                                          int K, __bf16* As, __bf16* Bs,
                                          f32x4 (&acc)[4][4], int row0, int col0) {
    int tid = threadIdx.x;
    int w = tid >> 6, l = tid & 63, l15 = l & 15, g = l >> 4;
    int wr = (w >> 1) << 6, wc = (w & 1) << 6;

    int sr0 = tid >> 2;
    int sr1 = 64 + (tid >> 2);
    int lc0 = (((tid & 3) ^ ((tid >> 3) & 3)) << 3); // swizzled source chunk
    const __bf16* gA0 = A + (size_t)(row0 + sr0) * K + lc0;
    const __bf16* gA1 = A + (size_t)(row0 + sr1) * K + lc0;
    const __bf16* gB0 = Bt + (size_t)(col0 + sr0) * K + lc0;
    const __bf16* gB1 = Bt + (size_t)(col0 + sr1) * K + lc0;
    __bf16* lA0 = As + w * 512;
    __bf16* lA1 = As + 2048 + w * 512;
    __bf16* lB0 = Bs + w * 512;
    __bf16* lB1 = Bs + 2048 + w * 512;

    int rca = ((g ^ ((l15 >> 1) & 3)) << 3); // swizzled read chunk

#pragma unroll
    for (int i = 0; i < 4; ++i)
#pragma unroll
        for (int j = 0; j < 4; ++j) acc[i][j] = f4zero();

    for (int k0 = 0; k0 < K; k0 += 32) {
        __syncthreads();
        GLOAD_LDS16(gA0 + k0, lA0);
        GLOAD_LDS16(gA1 + k0, lA1);
        GLOAD_LDS16(gB0 + k0, lB0);
        GLOAD_LDS16(gB1 + k0, lB1);
        __syncthreads();

        bf16x8 af[4], bfr[4];
#pragma unroll
        for (int i = 0; i < 4; ++i) af[i] = *(const bf16x8*)&As[(wr + i * 16 + l15) * 32 + rca];
#pragma unroll
        for (int j = 0; j < 4; ++j) bfr[j] = *(const bf16x8*)&Bs[(wc + j * 16 + l15) * 32 + rca];
        __builtin_amdgcn_s_setprio(1);
#pragma unroll
        for (int i = 0; i < 4; ++i)
#pragma unroll
            for (int j = 0; j < 4; ++j)
                acc[i][j] = __builtin_amdgcn_mfma_f32_16x16x32_bf16(af[i], bfr[j], acc[i][j], 0, 0, 0);
        __builtin_amdgcn_s_setprio(0);
    }
}

// QKV GEMM: z=0 (Q, +RoPE), z=1 (K, +RoPE), z=2 (V, transposed write to vt)
__global__ __launch_bounds__(256) void gemm_qkv_kernel(const __bf16* __restrict__ xn,
                                                       const __bf16* __restrict__ wq,
                                                       const __bf16* __restrict__ wk,
                                                       const __bf16* __restrict__ wv,
                                                       __bf16* __restrict__ qo,
                                                       __bf16* __restrict__ ko,
                                                       __bf16* __restrict__ vt,
                                                       const float* __restrict__ cosT,
                                                       const float* __restrict__ sinT) {
    __shared__ __bf16 As[128 * 32];
    __shared__ __bf16 Bs[128 * 32];
    int z = blockIdx.z;
    const __bf16* Bt = z == 0 ? wq : z == 1 ? wk : wv;
    int row0 = (int)blockIdx.y << 7, col0 = (int)blockIdx.x << 7;
    f32x4 acc[4][4];
    gemm_core(xn, Bt, DIM, As, Bs, acc, row0, col0);

    int tid = threadIdx.x;
    int w = tid >> 6, l = tid & 63, l15 = l & 15, g = l >> 4;
    int wr = (w >> 1) << 6, wc = (w & 1) << 6;
    int colbase = col0 + wc;

    if (z == 2) {
        // V: write transposed into vt[bh][d][s]
        int bh = ((row0 >> 11) << 4) + (colbase >> 6);
#pragma unroll
        for (int i = 0; i < 4; ++i) {
            int sbase = (row0 + wr + i * 16 + g * 4) & (SEQ - 1);
#pragma unroll
            for (int j = 0; j < 4; ++j) {
                int d = j * 16 + l15;
                bf16x4 o;
#pragma unroll
                for (int r = 0; r < 4; ++r) o[r] = (__bf16)acc[i][j][r];
                *(bf16x4*)&vt[((size_t)bh * HD + d) * SEQ + sbase] = o;
            }
        }
    } else {
        __bf16* C = z == 0 ? qo : ko;
#pragma unroll
        for (int i = 0; i < 4; ++i) {
#pragma unroll
            for (int r = 0; r < 4; ++r) {
                int row = row0 + wr + i * 16 + g * 4 + r;
                int s = row & (SEQ - 1);
#pragma unroll
                for (int j = 0; j < 2; ++j) {
                    float c = cosT[s * 32 + j * 16 + l15];
                    float sn = sinT[s * 32 + j * 16 + l15];
                    float x1 = acc[i][j][r], x2 = acc[i][j + 2][r];
                    C[(size_t)row * DIM + colbase + j * 16 + l15] = (__bf16)(x1 * c - x2 * sn);
                    C[(size_t)row * DIM + colbase + (j + 2) * 16 + l15] = (__bf16)(x1 * sn + x2 * c);
                }
            }
        }
    }
}

__global__ __launch_bounds__(256) void gemm_out_kernel(const __bf16* __restrict__ ctx,
                                                       const __bf16* __restrict__ wo,
                                                       float* __restrict__ out) {
    __shared__ __bf16 As[128 * 32];
    __shared__ __bf16 Bs[128 * 32];
    int row0 = (int)blockIdx.y << 7, col0 = (int)blockIdx.x << 7;
    f32x4 acc[4][4];
    gemm_core(ctx, wo, DIM, As, Bs, acc, row0, col0);
    int tid = threadIdx.x;
    int w = tid >> 6, l = tid & 63, l15 = l & 15, g = l >> 4;
    int wr = (w >> 1) << 6, wc = (w & 1) << 6;
#pragma unroll
    for (int i = 0; i < 4; ++i)
#pragma unroll
        for (int j = 0; j < 4; ++j)
#pragma unroll
            for (int r = 0; r < 4; ++r) {
                int row = row0 + wr + i * 16 + g * 4 + r;
                int col = col0 + wc + j * 16 + l15;
                out[(size_t)row * DIM + col] = acc[i][j][r];
            }
}

// ---------------- Swapped-operand 32x32 MFMA causal flash attention ----------------
// 4 waves x 32 q-rows (block = 128 rows), KVBLK=64. S^T = mfma(K,Q) -> lane owns
// one q-row (lane&31); softmax in-lane + one shfl_xor(32); P packed to bf16 B-frags
// via cvt_pk + permlane32_swap; O^T = mfma(V^T, P) -> lane-uniform rescale.
__global__ __launch_bounds__(256) void attn_mfma_kernel(const __bf16* __restrict__ q,
                                                        const __bf16* __restrict__ k,
                                                        const __bf16* __restrict__ vt,
                                                        __bf16* __restrict__ ctx) {
    int bh = blockIdx.x;
    int qb = 15 - (int)blockIdx.y; // heavy blocks dispatch first
    int b = bh >> 4, h = bh & 15;
    __shared__ __bf16 Ks[64][72]; // [s_local][d]
    __shared__ __bf16 Vs[64][72]; // [d][s_local]
    int tid = threadIdx.x, w = tid >> 6, l = tid & 63;
    int l31 = l & 31, hi = l >> 5;
    size_t hoff = (size_t)(b * SEQ) * DIM + h * HD;
    const __bf16* vth = vt + (size_t)bh * HD * SEQ;
    int qw0 = qb * 128 + w * 32;
    int qrow = qw0 + l31;
    int qmax = qw0 + 31;
    int nst = 2 * qb + 2;

    // Q B-frags, pre-scaled by 0.125*log2(e) -> QK^T lands in exp2 domain
    bf16x8 qf[4];
    const float c2 = 0.125f * 1.44269504f;
#pragma unroll
    for (int g = 0; g < 4; ++g) {
        bf16x8 t0 = *(const bf16x8*)&q[hoff + (size_t)qrow * DIM + g * 16 + hi * 8];
#pragma unroll
        for (int e = 0; e < 8; ++e) qf[g][e] = (__bf16)((float)t0[e] * c2);
    }

    f32x16 oA, oB;
#pragma unroll
    for (int r = 0; r < 16; ++r) {
        oA[r] = 0.f;
        oB[r] = 0.f;
    }
    float m_run = -1e30f, l_run = 0.f;

    // staging: 2 chunks each of K and V^T per thread
    int sr = tid >> 3, sc = (tid & 7) * 8;
    bf16x8 rk0, rk1, rv0, rv1;
    rk0 = *(const bf16x8*)&k[hoff + (size_t)sr * DIM + sc];
    rk1 = *(const bf16x8*)&k[hoff + (size_t)(32 + sr) * DIM + sc];
    rv0 = *(const bf16x8*)&vth[(size_t)sr * SEQ + sc];
    rv1 = *(const bf16x8*)&vth[(size_t)(32 + sr) * SEQ + sc];

    for (int st = 0; st < nst; ++st) {
        int s0 = st << 6;
        __syncthreads();
        *(bf16x8*)&Ks[sr][sc] = rk0;
        *(bf16x8*)&Ks[32 + sr][sc] = rk1;
        *(bf16x8*)&Vs[sr][sc] = rv0;
        *(bf16x8*)&Vs[32 + sr][sc] = rv1;
        __syncthreads();
        if (st + 1 < nst) {
            int sn = s0 + 64;
            rk0 = *(const bf16x8*)&k[hoff + (size_t)(sn + sr) * DIM + sc];
            rk1 = *(const bf16x8*)&k[hoff + (size_t)(sn + 32 + sr) * DIM + sc];
            rv0 = *(const bf16x8*)&vth[(size_t)sr * SEQ + sn + sc];
            rv1 = *(const bf16x8*)&vth[(size_t)(32 + sr) * SEQ + sn + sc];
        }
        if (s0 > qmax) continue; // wave inactive on this tile (barriers already done)

        // S^T = mfma(K, Q): sa = k-rows 0..31, sb = 32..63 (cols = q = lane&31)
        f32x16 sa, sb;
#pragma unroll
        for (int r = 0; r < 16; ++r) {
            sa[r] = 0.f;
            sb[r] = 0.f;
        }
        __builtin_amdgcn_s_setprio(1);
#pragma unroll
        for (int g = 0; g < 4; ++g) {
            bf16x8 ka = *(const bf16x8*)&Ks[l31][g * 16 + hi * 8];
            bf16x8 kb2 = *(const bf16x8*)&Ks[32 + l31][g * 16 + hi * 8];
            sa = __builtin_amdgcn_mfma_f32_32x32x16_bf16(ka, qf[g], sa, 0, 0, 0);
            sb = __builtin_amdgcn_mfma_f32_32x32x16_bf16(kb2, qf[g], sb, 0, 0, 0);
        }
        __builtin_amdgcn_s_setprio(0);

        if (s0 + 63 > qw0) { // causal mask (diagonal region only)
#pragma unroll
            for (int r = 0; r < 16; ++r) {
                int kg = s0 + (r & 3) + 8 * (r >> 2) + 4 * hi;
                if (kg > qrow) sa[r] = -1e30f;
                if (kg + 32 > qrow) sb[r] = -1e30f;
            }
        }

        // online softmax (exp2 domain), defer-max THR=10
        float lmax = -3e38f;
#pragma unroll
        for (int r = 0; r < 16; ++r) lmax = fmaxf(lmax, fmaxf(sa[r], sb[r]));
        if (!__all(lmax <= m_run + 10.0f)) {
            float omax = fmaxf(lmax, __shfl_xor(lmax, 32));
            float m_new = fmaxf(m_run, omax);
            float alpha = exp2f(m_run - m_new);
            l_run *= alpha;
#pragma unroll
            for (int r = 0; r < 16; ++r) {
                oA[r] *= alpha;
                oB[r] *= alpha;
            }
            m_run = m_new;
        }
        float ls = 0.f;
#pragma unroll
        for (int r = 0; r < 16; ++r) {
            sa[r] = exp2f(sa[r] - m_run);
            ls += sa[r];
            sb[r] = exp2f(sb[r] - m_run);
            ls += sb[r];
        }
        l_run += ls + __shfl_xor(ls, 32);

        // pack P -> bf16 B-frags: pa[ks] = P[q=lane&31][ks*16 + hi*8 + 0..7]
        bf16x8 pa[4];
#pragma unroll
        for (int g = 0; g < 2; ++g) {
            unsigned a_ = cvtpk(sa[8 * g + 0], sa[8 * g + 1]);
            unsigned b_ = cvtpk(sa[8 * g + 4], sa[8 * g + 5]);
            pl32swap(a_, b_);
            unsigned c_ = cvtpk(sa[8 * g + 2], sa[8 * g + 3]);
            unsigned d_ = cvtpk(sa[8 * g + 6], sa[8 * g + 7]);
            pl32swap(c_, d_);
            u32x4 t4 = {a_, c_, b_, d_};
            pa[g] = __builtin_bit_cast(bf16x8, t4);
        }
#pragma unroll
        for (int g = 0; g < 2; ++g) {
            unsigned a_ = cvtpk(sb[8 * g + 0], sb[8 * g + 1]);
            unsigned b_ = cvtpk(sb[8 * g + 4], sb[8 * g + 5]);
            pl32swap(a_, b_);
            unsigned c_ = cvtpk(sb[8 * g + 2], sb[8 * g + 3]);
            unsigned d_ = cvtpk(sb[8 * g + 6], sb[8 * g + 7]);
            pl32swap(c_, d_);
            u32x4 t4 = {a_, c_, b_, d_};
            pa[2 + g] = __builtin_bit_cast(bf16x8, t4);
        }

        // O^T += mfma(V^T, P): oA = d 0..31, oB = d 32..63 (cols = q = lane&31)
        __builtin_amdgcn_s_setprio(1);
#pragma unroll
        for (int ks = 0; ks < 4; ++ks) {
            bf16x8 va = *(const bf16x8*)&Vs[l31][ks * 16 + hi * 8];
            bf16x8 vb2 = *(const bf16x8*)&Vs[32 + l31][ks * 16 + hi * 8];
            oA = __builtin_amdgcn_mfma_f32_32x32x16_bf16(va, pa[ks], oA, 0, 0, 0);
            oB = __builtin_amdgcn_mfma_f32_32x32x16_bf16(vb2, pa[ks], oB, 0, 0, 0);
        }
        __builtin_amdgcn_s_setprio(0);
    }

    float inv = 1.0f / l_run;
#pragma unroll
    for (int r = 0; r < 16; r += 2) {
        int d = (r & 3) + 8 * (r >> 2) + 4 * hi;
        unsigned pA = cvtpk(oA[r] * inv, oA[r + 1] * inv);
        unsigned pB = cvtpk(oB[r] * inv, oB[r + 1] * inv);
        *(unsigned*)&ctx[hoff + (size_t)qrow * DIM + d] = pA;
        *(unsigned*)&ctx[hoff + (size_t)qrow * DIM + 32 + d] = pB;
    }
}

extern "C" void kernel_launch(void* const* d_in, const int* in_sizes, int n_in,
                              void* d_out, int out_size, void* d_ws, size_t ws_size,
                              hipStream_t stream) {
    const float* x = (const float*)d_in[0];
    const float* w_norm = (const float*)d_in[1];
    const float* Wq = (const float*)d_in[2];
    const float* Wk = (const float*)d_in[3];
    const float* Wv = (const float*)d_in[4];
    const float* Wo = (const float*)d_in[5];
    float* out = (float*)d_out;
    char* w8 = (char*)d_ws;

    __bf16* xn = (__bf16*)(w8);                 // 8 MB
    __bf16* wtq = (__bf16*)(w8 + (8ull << 20)); // 2 MB each
    __bf16* wtk = (__bf16*)(w8 + (10ull << 20));
    __bf16* wtv = (__bf16*)(w8 + (12ull << 20));
    __bf16* wto = (__bf16*)(w8 + (14ull << 20));
    __bf16* qb = (__bf16*)(w8 + (16ull << 20)); // 8 MB each
    __bf16* kb = (__bf16*)(w8 + (24ull << 20));
    __bf16* vtb = (__bf16*)(w8 + (32ull << 20));
    __bf16* ctx = (__bf16*)(w8 + (40ull << 20));
    float* cosT = (float*)(w8 + (48ull << 20));
    float* sinT = cosT + SEQ * 32;

    wcvt_kernel<<<dim3(32, 32, 4), 256, 0, stream>>>(Wq, Wk, Wv, Wo, wtq, wtk, wtv, wto);
    rmsnorm_bf16<<<ROWS, 256, 0, stream>>>(x, w_norm, xn);
    rope_table_kernel<<<(SEQ * 32) / 256, 256, 0, stream>>>(cosT, sinT);

    gemm_qkv_kernel<<<dim3(DIM / 128, ROWS / 128, 3), 256, 0, stream>>>(
        xn, wtq, wtk, wtv, qb, kb, vtb, cosT, sinT);

    attn_mfma_kernel<<<dim3(BATCH * NHEADS, SEQ / 128), 256, 0, stream>>>(qb, kb, vtb, ctx);

    gemm_out_kernel<<<dim3(DIM / 128, ROWS / 128), 256, 0, stream>>>(ctx, wto, out);
}

// Round 6
// 137.457 us; speedup vs baseline: 1.0970x; 1.0970x over previous
//
#include <hip/hip_runtime.h>

#define DIM 1024
#define SEQ 2048
#define BATCH 2
#define NHEADS 16
#define HD 64
#define ROWS (BATCH * SEQ) // 4096

typedef __bf16 bf16x8 __attribute__((ext_vector_type(8)));
typedef __bf16 bf16x4 __attribute__((ext_vector_type(4)));
typedef float f32x4 __attribute__((ext_vector_type(4)));
typedef float f32x16 __attribute__((ext_vector_type(16)));
typedef unsigned u32x4 __attribute__((ext_vector_type(4)));

__device__ __forceinline__ f32x4 f4zero() {
    f32x4 z = {0.f, 0.f, 0.f, 0.f};
    return z;
}

__device__ __forceinline__ unsigned cvtpk(float lo, float hi) {
    unsigned r;
    asm("v_cvt_pk_bf16_f32 %0, %1, %2" : "=v"(r) : "v"(lo), "v"(hi));
    return r;
}

__device__ __forceinline__ void pl32swap(unsigned& a, unsigned& b) {
    asm volatile("v_permlane32_swap_b32 %0, %1" : "+v"(a), "+v"(b));
}

#define GLOAD_LDS16(g, l)                                                                  \
    __builtin_amdgcn_global_load_lds((const __attribute__((address_space(1))) void*)(g),   \
                                     (__attribute__((address_space(3))) void*)(l), 16, 0, 0)

// ---------------- RMSNorm -> bf16 ----------------
__global__ __launch_bounds__(256) void rmsnorm_bf16(const float* __restrict__ x,
                                                    const float* __restrict__ w,
                                                    __bf16* __restrict__ xn) {
    int row = blockIdx.x;
    int t = threadIdx.x;
    float4 v = ((const float4*)(x + (size_t)row * DIM))[t];
    float ss = v.x * v.x + v.y * v.y + v.z * v.z + v.w * v.w;
#pragma unroll
    for (int off = 1; off < 64; off <<= 1) ss += __shfl_xor(ss, off);
    __shared__ float red[4];
    if ((t & 63) == 0) red[t >> 6] = ss;
    __syncthreads();
    ss = red[0] + red[1] + red[2] + red[3];
    float scale = rsqrtf(ss * (1.0f / DIM) + 1e-5f);
    float4 wv = ((const float4*)w)[t];
    bf16x4 o;
    o[0] = (__bf16)(v.x * scale * wv.x);
    o[1] = (__bf16)(v.y * scale * wv.y);
    o[2] = (__bf16)(v.z * scale * wv.z);
    o[3] = (__bf16)(v.w * scale * wv.w);
    *(bf16x4*)(xn + (size_t)row * DIM + t * 4) = o;
}

// ---------------- Weight convert + transpose: W[k][n] f32 -> Wt[n][k] bf16 ----------------
__global__ __launch_bounds__(256) void wcvt_kernel(const float* __restrict__ Wq,
                                                   const float* __restrict__ Wk,
                                                   const float* __restrict__ Wv,
                                                   const float* __restrict__ Wo,
                                                   __bf16* tq, __bf16* tk, __bf16* tv, __bf16* to_) {
    int z = blockIdx.z;
    const float* W = z == 0 ? Wq : z == 1 ? Wk : z == 2 ? Wv : Wo;
    __bf16* T = z == 0 ? tq : z == 1 ? tk : z == 2 ? tv : to_;
    __shared__ float tile[32][33];
    int n0 = blockIdx.x * 32, k0 = blockIdx.y * 32;
    int tx = threadIdx.x & 31, ty = threadIdx.x >> 5;
#pragma unroll
    for (int j = 0; j < 32; j += 8) tile[ty + j][tx] = W[(size_t)(k0 + ty + j) * DIM + n0 + tx];
    __syncthreads();
#pragma unroll
    for (int j = 0; j < 32; j += 8)
        T[(size_t)(n0 + ty + j) * DIM + k0 + tx] = (__bf16)tile[tx][ty + j];
}

// ---------------- RoPE table ----------------
__global__ __launch_bounds__(256) void rope_table_kernel(float* __restrict__ cosT,
                                                         float* __restrict__ sinT) {
    int idx = blockIdx.x * 256 + threadIdx.x; // SEQ*32
    int s = idx >> 5, i = idx & 31;
    float e = (2.0f * (float)i) / 64.0f;
    float theta = 1.0f / powf(1000000.0f, e);
    float ang = (float)s * theta;
    cosT[idx] = cosf(ang);
    sinT[idx] = sinf(ang);
}

// ---------------- MFMA GEMM core (m97-style), acc left in registers ----------------
__device__ __forceinline__ void gemm_core(const __bf16* __restrict__ A,
                                          const __bf16* __restrict__ Bt,
                                          int K, __bf16* As, __bf16* Bs,
                                          f32x4 (&acc)[4][4], int row0, int col0) {
    int tid = threadIdx.x;
    int w = tid >> 6, l = tid & 63, l15 = l & 15, g = l >> 4;
    int wr = (w >> 1) << 6, wc = (w & 1) << 6;

    int sr0 = tid >> 2;
    int sr1 = 64 + (tid >> 2);
    int lc0 = (((tid & 3) ^ ((tid >> 3) & 3)) << 3); // swizzled source chunk
    const __bf16* gA0 = A + (size_t)(row0 + sr0) * K + lc0;
    const __bf16* gA1 = A + (size_t)(row0 + sr1) * K + lc0;
    const __bf16* gB0 = Bt + (size_t)(col0 + sr0) * K + lc0;
    const __bf16* gB1 = Bt + (size_t)(col0 + sr1) * K + lc0;
    __bf16* lA0 = As + w * 512;
    __bf16* lA1 = As + 2048 + w * 512;
    __bf16* lB0 = Bs + w * 512;
    __bf16* lB1 = Bs + 2048 + w * 512;

    int rca = ((g ^ ((l15 >> 1) & 3)) << 3); // swizzled read chunk

#pragma unroll
    for (int i = 0; i < 4; ++i)
#pragma unroll
        for (int j = 0; j < 4; ++j) acc[i][j] = f4zero();

    for (int k0 = 0; k0 < K; k0 += 32) {
        __syncthreads();
        GLOAD_LDS16(gA0 + k0, lA0);
        GLOAD_LDS16(gA1 + k0, lA1);
        GLOAD_LDS16(gB0 + k0, lB0);
        GLOAD_LDS16(gB1 + k0, lB1);
        __syncthreads();

        bf16x8 af[4], bfr[4];
#pragma unroll
        for (int i = 0; i < 4; ++i) af[i] = *(const bf16x8*)&As[(wr + i * 16 + l15) * 32 + rca];
#pragma unroll
        for (int j = 0; j < 4; ++j) bfr[j] = *(const bf16x8*)&Bs[(wc + j * 16 + l15) * 32 + rca];
        __builtin_amdgcn_s_setprio(1);
#pragma unroll
        for (int i = 0; i < 4; ++i)
#pragma unroll
            for (int j = 0; j < 4; ++j)
                acc[i][j] = __builtin_amdgcn_mfma_f32_16x16x32_bf16(af[i], bfr[j], acc[i][j], 0, 0, 0);
        __builtin_amdgcn_s_setprio(0);
    }
}

// Fused QKV GEMM, 1D grid of 768 blocks:
//  bid <  512: Q/K (z = bid>>8) with RoPE epilogue, C row-major [row][DIM]
//  bid >= 512: V computed TRANSPOSED: vt[b*1024 + n][s] = sum_k wtv[n][k]*xn_b[s][k]
__global__ __launch_bounds__(256) void gemm_qkv_kernel(const __bf16* __restrict__ xn,
                                                       const __bf16* __restrict__ wq,
                                                       const __bf16* __restrict__ wk,
                                                       const __bf16* __restrict__ wv,
                                                       __bf16* __restrict__ qo,
                                                       __bf16* __restrict__ ko,
                                                       __bf16* __restrict__ vt,
                                                       const float* __restrict__ cosT,
                                                       const float* __restrict__ sinT) {
    __shared__ __bf16 As[128 * 32];
    __shared__ __bf16 Bs[128 * 32];
    int bid = blockIdx.x;
    int tid = threadIdx.x;
    int w = tid >> 6, l = tid & 63, l15 = l & 15, g = l >> 4;
    int wr = (w >> 1) << 6, wc = (w & 1) << 6;
    f32x4 acc[4][4];

    if (bid < 512) {
        int z = bid >> 8, t = bid & 255;
        int col0 = (t & 7) << 7, row0 = (t >> 3) << 7;
        gemm_core(xn, z ? wk : wq, DIM, As, Bs, acc, row0, col0);
        __bf16* C = z ? ko : qo;
        int colbase = col0 + wc;
#pragma unroll
        for (int i = 0; i < 4; ++i) {
#pragma unroll
            for (int r = 0; r < 4; ++r) {
                int row = row0 + wr + i * 16 + g * 4 + r;
                int s = row & (SEQ - 1);
#pragma unroll
                for (int j = 0; j < 2; ++j) {
                    float c = cosT[s * 32 + j * 16 + l15];
                    float sn = sinT[s * 32 + j * 16 + l15];
                    float x1 = acc[i][j][r], x2 = acc[i][j + 2][r];
                    C[(size_t)row * DIM + colbase + j * 16 + l15] = (__bf16)(x1 * c - x2 * sn);
                    C[(size_t)row * DIM + colbase + (j + 2) * 16 + l15] = (__bf16)(x1 * sn + x2 * c);
                }
            }
        }
    } else {
        int t = bid - 512;           // 256 blocks: [batch 2][n-blocks 8][s-blocks 16]
        int b = t >> 7, r7 = t & 127;
        int row0 = (r7 >> 4) << 7;   // n
        int col0 = (r7 & 15) << 7;   // s
        gemm_core(wv, xn + (size_t)b * SEQ * DIM, DIM, As, Bs, acc, row0, col0);
        __bf16* C = vt + (size_t)b * (NHEADS * HD) * SEQ;
#pragma unroll
        for (int i = 0; i < 4; ++i)
#pragma unroll
            for (int j = 0; j < 4; ++j)
#pragma unroll
                for (int r = 0; r < 4; ++r) {
                    int row = row0 + wr + i * 16 + g * 4 + r;
                    int col = col0 + wc + j * 16 + l15;
                    C[(size_t)row * SEQ + col] = (__bf16)acc[i][j][r];
                }
    }
}

__global__ __launch_bounds__(256) void gemm_out_kernel(const __bf16* __restrict__ ctx,
                                                       const __bf16* __restrict__ wo,
                                                       float* __restrict__ out) {
    __shared__ __bf16 As[128 * 32];
    __shared__ __bf16 Bs[128 * 32];
    int row0 = (int)blockIdx.y << 7, col0 = (int)blockIdx.x << 7;
    f32x4 acc[4][4];
    gemm_core(ctx, wo, DIM, As, Bs, acc, row0, col0);
    int tid = threadIdx.x;
    int w = tid >> 6, l = tid & 63, l15 = l & 15, g = l >> 4;
    int wr = (w >> 1) << 6, wc = (w & 1) << 6;
#pragma unroll
    for (int i = 0; i < 4; ++i)
#pragma unroll
        for (int j = 0; j < 4; ++j)
#pragma unroll
            for (int r = 0; r < 4; ++r) {
                int row = row0 + wr + i * 16 + g * 4 + r;
                int col = col0 + wc + j * 16 + l15;
                out[(size_t)row * DIM + col] = acc[i][j][r];
            }
}

// ---------------- Swapped-operand 32x32 MFMA causal flash attention ----------------
// 2 waves x 32 q-rows (block = 64 rows), KVBLK=64, grid 32bh x 32qt.
// S^T = mfma(K,Q) -> lane owns one q-row; softmax in-lane + one shfl_xor(32);
// P packed via cvt_pk + permlane32_swap; O^T = mfma(V^T, P).
__global__ __launch_bounds__(128) void attn_mfma_kernel(const __bf16* __restrict__ q,
                                                        const __bf16* __restrict__ k,
                                                        const __bf16* __restrict__ vt,
                                                        __bf16* __restrict__ ctx) {
    int bh = blockIdx.x;
    int qb = 31 - (int)blockIdx.y; // heavy blocks dispatch first
    int b = bh >> 4, h = bh & 15;
    __shared__ __bf16 Ks[64][72]; // [s_local][d]
    __shared__ __bf16 Vs[64][72]; // [d][s_local]
    int tid = threadIdx.x, w = tid >> 6, l = tid & 63;
    int l31 = l & 31, hi = l >> 5;
    size_t hoff = (size_t)(b * SEQ) * DIM + h * HD;
    const __bf16* vth = vt + (size_t)bh * HD * SEQ;
    int qw0 = qb * 64 + w * 32;
    int qrow = qw0 + l31;
    int nst = qb + 1;

    // Q B-frags, pre-scaled by 0.125*log2(e) -> QK^T lands in exp2 domain
    bf16x8 qf[4];
    const float c2 = 0.125f * 1.44269504f;
#pragma unroll
    for (int g = 0; g < 4; ++g) {
        bf16x8 t0 = *(const bf16x8*)&q[hoff + (size_t)qrow * DIM + g * 16 + hi * 8];
#pragma unroll
        for (int e = 0; e < 8; ++e) qf[g][e] = (__bf16)((float)t0[e] * c2);
    }

    f32x16 oA, oB;
#pragma unroll
    for (int r = 0; r < 16; ++r) {
        oA[r] = 0.f;
        oB[r] = 0.f;
    }
    float m_run = -1e30f, l_run = 0.f;

    // staging: 128 threads, 4 chunks each of K and V^T (rows c*16+sr)
    int sr = tid >> 3, sc = (tid & 7) * 8;
    bf16x8 rk[4], rv[4];
#pragma unroll
    for (int c = 0; c < 4; ++c) {
        rk[c] = *(const bf16x8*)&k[hoff + (size_t)(c * 16 + sr) * DIM + sc];
        rv[c] = *(const bf16x8*)&vth[(size_t)(c * 16 + sr) * SEQ + sc];
    }

    for (int st = 0; st < nst; ++st) {
        int s0 = st << 6;
        __syncthreads();
#pragma unroll
        for (int c = 0; c < 4; ++c) {
            *(bf16x8*)&Ks[c * 16 + sr][sc] = rk[c];
            *(bf16x8*)&Vs[c * 16 + sr][sc] = rv[c];
        }
        __syncthreads();
        if (st + 1 < nst) {
            int sn = s0 + 64;
#pragma unroll
            for (int c = 0; c < 4; ++c) {
                rk[c] = *(const bf16x8*)&k[hoff + (size_t)(sn + c * 16 + sr) * DIM + sc];
                rv[c] = *(const bf16x8*)&vth[(size_t)(c * 16 + sr) * SEQ + sn + sc];
            }
        }

        // S^T = mfma(K, Q): sa = k-rows 0..31, sb = 32..63 (cols = q = lane&31)
        f32x16 sa, sb;
#pragma unroll
        for (int r = 0; r < 16; ++r) {
            sa[r] = 0.f;
            sb[r] = 0.f;
        }
        __builtin_amdgcn_s_setprio(1);
#pragma unroll
        for (int g = 0; g < 4; ++g) {
            bf16x8 ka = *(const bf16x8*)&Ks[l31][g * 16 + hi * 8];
            bf16x8 kb2 = *(const bf16x8*)&Ks[32 + l31][g * 16 + hi * 8];
            sa = __builtin_amdgcn_mfma_f32_32x32x16_bf16(ka, qf[g], sa, 0, 0, 0);
            sb = __builtin_amdgcn_mfma_f32_32x32x16_bf16(kb2, qf[g], sb, 0, 0, 0);
        }
        __builtin_amdgcn_s_setprio(0);

        if (s0 + 63 > qw0) { // causal mask (diagonal region only)
#pragma unroll
            for (int r = 0; r < 16; ++r) {
                int kg = s0 + (r & 3) + 8 * (r >> 2) + 4 * hi;
                if (kg > qrow) sa[r] = -1e30f;
                if (kg + 32 > qrow) sb[r] = -1e30f;
            }
        }

        // online softmax (exp2 domain), defer-max THR=10
        float lmax = -3e38f;
#pragma unroll
        for (int r = 0; r < 16; ++r) lmax = fmaxf(lmax, fmaxf(sa[r], sb[r]));
        if (!__all(lmax <= m_run + 10.0f)) {
            float omax = fmaxf(lmax, __shfl_xor(lmax, 32));
            float m_new = fmaxf(m_run, omax);
            float alpha = exp2f(m_run - m_new);
            l_run *= alpha;
#pragma unroll
            for (int r = 0; r < 16; ++r) {
                oA[r] *= alpha;
                oB[r] *= alpha;
            }
            m_run = m_new;
        }
        float ls = 0.f;
#pragma unroll
        for (int r = 0; r < 16; ++r) {
            sa[r] = exp2f(sa[r] - m_run);
            ls += sa[r];
            sb[r] = exp2f(sb[r] - m_run);
            ls += sb[r];
        }
        l_run += ls + __shfl_xor(ls, 32);

        // pack P -> bf16 B-frags: pa[ks] = P[q=lane&31][ks*16 + hi*8 + 0..7]
        bf16x8 pa[4];
#pragma unroll
        for (int g = 0; g < 2; ++g) {
            unsigned a_ = cvtpk(sa[8 * g + 0], sa[8 * g + 1]);
            unsigned b_ = cvtpk(sa[8 * g + 4], sa[8 * g + 5]);
            pl32swap(a_, b_);
            unsigned c_ = cvtpk(sa[8 * g + 2], sa[8 * g + 3]);
            unsigned d_ = cvtpk(sa[8 * g + 6], sa[8 * g + 7]);
            pl32swap(c_, d_);
            u32x4 t4 = {a_, c_, b_, d_};
            pa[g] = __builtin_bit_cast(bf16x8, t4);
        }
#pragma unroll
        for (int g = 0; g < 2; ++g) {
            unsigned a_ = cvtpk(sb[8 * g + 0], sb[8 * g + 1]);
            unsigned b_ = cvtpk(sb[8 * g + 4], sb[8 * g + 5]);
            pl32swap(a_, b_);
            unsigned c_ = cvtpk(sb[8 * g + 2], sb[8 * g + 3]);
            unsigned d_ = cvtpk(sb[8 * g + 6], sb[8 * g + 7]);
            pl32swap(c_, d_);
            u32x4 t4 = {a_, c_, b_, d_};
            pa[2 + g] = __builtin_bit_cast(bf16x8, t4);
        }

        // O^T += mfma(V^T, P): oA = d 0..31, oB = d 32..63 (cols = q = lane&31)
        __builtin_amdgcn_s_setprio(1);
#pragma unroll
        for (int ks = 0; ks < 4; ++ks) {
            bf16x8 va = *(const bf16x8*)&Vs[l31][ks * 16 + hi * 8];
            bf16x8 vb2 = *(const bf16x8*)&Vs[32 + l31][ks * 16 + hi * 8];
            oA = __builtin_amdgcn_mfma_f32_32x32x16_bf16(va, pa[ks], oA, 0, 0, 0);
            oB = __builtin_amdgcn_mfma_f32_32x32x16_bf16(vb2, pa[ks], oB, 0, 0, 0);
        }
        __builtin_amdgcn_s_setprio(0);
    }

    float inv = 1.0f / l_run;
#pragma unroll
    for (int rr = 0; rr < 16; rr += 4) {
        int d = 8 * (rr >> 2) + 4 * hi; // (rr&3)==0 base; d..d+3 contiguous
        uint2 pA = {cvtpk(oA[rr] * inv, oA[rr + 1] * inv), cvtpk(oA[rr + 2] * inv, oA[rr + 3] * inv)};
        uint2 pB = {cvtpk(oB[rr] * inv, oB[rr + 1] * inv), cvtpk(oB[rr + 2] * inv, oB[rr + 3] * inv)};
        *(uint2*)&ctx[hoff + (size_t)qrow * DIM + d] = pA;
        *(uint2*)&ctx[hoff + (size_t)qrow * DIM + 32 + d] = pB;
    }
}

extern "C" void kernel_launch(void* const* d_in, const int* in_sizes, int n_in,
                              void* d_out, int out_size, void* d_ws, size_t ws_size,
                              hipStream_t stream) {
    const float* x = (const float*)d_in[0];
    const float* w_norm = (const float*)d_in[1];
    const float* Wq = (const float*)d_in[2];
    const float* Wk = (const float*)d_in[3];
    const float* Wv = (const float*)d_in[4];
    const float* Wo = (const float*)d_in[5];
    float* out = (float*)d_out;
    char* w8 = (char*)d_ws;

    __bf16* xn = (__bf16*)(w8);                 // 8 MB
    __bf16* wtq = (__bf16*)(w8 + (8ull << 20)); // 2 MB each
    __bf16* wtk = (__bf16*)(w8 + (10ull << 20));
    __bf16* wtv = (__bf16*)(w8 + (12ull << 20));
    __bf16* wto = (__bf16*)(w8 + (14ull << 20));
    __bf16* qb = (__bf16*)(w8 + (16ull << 20)); // 8 MB each
    __bf16* kb = (__bf16*)(w8 + (24ull << 20));
    __bf16* vtb = (__bf16*)(w8 + (32ull << 20));
    __bf16* ctx = (__bf16*)(w8 + (40ull << 20));
    float* cosT = (float*)(w8 + (48ull << 20));
    float* sinT = cosT + SEQ * 32;

    wcvt_kernel<<<dim3(32, 32, 4), 256, 0, stream>>>(Wq, Wk, Wv, Wo, wtq, wtk, wtv, wto);
    rmsnorm_bf16<<<ROWS, 256, 0, stream>>>(x, w_norm, xn);
    rope_table_kernel<<<(SEQ * 32) / 256, 256, 0, stream>>>(cosT, sinT);

    gemm_qkv_kernel<<<768, 256, 0, stream>>>(xn, wtq, wtk, wtv, qb, kb, vtb, cosT, sinT);

    attn_mfma_kernel<<<dim3(BATCH * NHEADS, SEQ / 64), 128, 0, stream>>>(qb, kb, vtb, ctx);

    gemm_out_kernel<<<dim3(DIM / 128, ROWS / 128), 256, 0, stream>>>(ctx, wto, out);
}

// Round 7
// 134.198 us; speedup vs baseline: 1.1237x; 1.0243x over previous
//
#include <hip/hip_runtime.h>

#define DIM 1024
#define SEQ 2048
#define BATCH 2
#define NHEADS 16
#define HD 64
#define ROWS (BATCH * SEQ) // 4096

typedef __bf16 bf16x8 __attribute__((ext_vector_type(8)));
typedef __bf16 bf16x4 __attribute__((ext_vector_type(4)));
typedef float f32x4 __attribute__((ext_vector_type(4)));
typedef float f32x16 __attribute__((ext_vector_type(16)));
typedef unsigned u32x4 __attribute__((ext_vector_type(4)));

__device__ __forceinline__ f32x4 f4zero() {
    f32x4 z = {0.f, 0.f, 0.f, 0.f};
    return z;
}

__device__ __forceinline__ unsigned cvtpk(float lo, float hi) {
    unsigned r;
    asm("v_cvt_pk_bf16_f32 %0, %1, %2" : "=v"(r) : "v"(lo), "v"(hi));
    return r;
}

__device__ __forceinline__ void pl32swap(unsigned& a, unsigned& b) {
    asm volatile("v_permlane32_swap_b32 %0, %1" : "+v"(a), "+v"(b));
}

// slot base within one bh: qb 0..7 -> 1 chunk, 8..15 -> 2, 16..23 -> 3, 24..31 -> 4 (80 total)
__device__ __forceinline__ int slot_base(int qb) {
    if (qb < 8) return qb;
    if (qb < 16) return 8 + 2 * (qb - 8);
    if (qb < 24) return 24 + 3 * (qb - 16);
    return 48 + 4 * (qb - 24);
}

#define GLOAD_LDS16(g, l)                                                                  \
    __builtin_amdgcn_global_load_lds((const __attribute__((address_space(1))) void*)(g),   \
                                     (__attribute__((address_space(3))) void*)(l), 16, 0, 0)

// ---------------- RMSNorm -> bf16 ----------------
__global__ __launch_bounds__(256) void rmsnorm_bf16(const float* __restrict__ x,
                                                    const float* __restrict__ w,
                                                    __bf16* __restrict__ xn) {
    int row = blockIdx.x;
    int t = threadIdx.x;
    float4 v = ((const float4*)(x + (size_t)row * DIM))[t];
    float ss = v.x * v.x + v.y * v.y + v.z * v.z + v.w * v.w;
#pragma unroll
    for (int off = 1; off < 64; off <<= 1) ss += __shfl_xor(ss, off);
    __shared__ float red[4];
    if ((t & 63) == 0) red[t >> 6] = ss;
    __syncthreads();
    ss = red[0] + red[1] + red[2] + red[3];
    float scale = rsqrtf(ss * (1.0f / DIM) + 1e-5f);
    float4 wv = ((const float4*)w)[t];
    bf16x4 o;
    o[0] = (__bf16)(v.x * scale * wv.x);
    o[1] = (__bf16)(v.y * scale * wv.y);
    o[2] = (__bf16)(v.z * scale * wv.z);
    o[3] = (__bf16)(v.w * scale * wv.w);
    *(bf16x4*)(xn + (size_t)row * DIM + t * 4) = o;
}

// ---------------- Weight convert + transpose: W[k][n] f32 -> Wt[n][k] bf16 ----------------
__global__ __launch_bounds__(256) void wcvt_kernel(const float* __restrict__ Wq,
                                                   const float* __restrict__ Wk,
                                                   const float* __restrict__ Wv,
                                                   const float* __restrict__ Wo,
                                                   __bf16* tq, __bf16* tk, __bf16* tv, __bf16* to_) {
    int z = blockIdx.z;
    const float* W = z == 0 ? Wq : z == 1 ? Wk : z == 2 ? Wv : Wo;
    __bf16* T = z == 0 ? tq : z == 1 ? tk : z == 2 ? tv : to_;
    __shared__ float tile[32][33];
    int n0 = blockIdx.x * 32, k0 = blockIdx.y * 32;
    int tx = threadIdx.x & 31, ty = threadIdx.x >> 5;
#pragma unroll
    for (int j = 0; j < 32; j += 8) tile[ty + j][tx] = W[(size_t)(k0 + ty + j) * DIM + n0 + tx];
    __syncthreads();
#pragma unroll
    for (int j = 0; j < 32; j += 8)
        T[(size_t)(n0 + ty + j) * DIM + k0 + tx] = (__bf16)tile[tx][ty + j];
}

// ---------------- RoPE table ----------------
__global__ __launch_bounds__(256) void rope_table_kernel(float* __restrict__ cosT,
                                                         float* __restrict__ sinT) {
    int idx = blockIdx.x * 256 + threadIdx.x; // SEQ*32
    int s = idx >> 5, i = idx & 31;
    float e = (2.0f * (float)i) / 64.0f;
    float theta = 1.0f / powf(1000000.0f, e);
    float ang = (float)s * theta;
    cosT[idx] = cosf(ang);
    sinT[idx] = sinf(ang);
}

// ---------------- MFMA GEMM core (m97-style), acc left in registers ----------------
__device__ __forceinline__ void gemm_core(const __bf16* __restrict__ A,
                                          const __bf16* __restrict__ Bt,
                                          int K, __bf16* As, __bf16* Bs,
                                          f32x4 (&acc)[4][4], int row0, int col0) {
    int tid = threadIdx.x;
    int w = tid >> 6, l = tid & 63, l15 = l & 15, g = l >> 4;
    int wr = (w >> 1) << 6, wc = (w & 1) << 6;

    int sr0 = tid >> 2;
    int sr1 = 64 + (tid >> 2);
    int lc0 = (((tid & 3) ^ ((tid >> 3) & 3)) << 3); // swizzled source chunk
    const __bf16* gA0 = A + (size_t)(row0 + sr0) * K + lc0;
    const __bf16* gA1 = A + (size_t)(row0 + sr1) * K + lc0;
    const __bf16* gB0 = Bt + (size_t)(col0 + sr0) * K + lc0;
    const __bf16* gB1 = Bt + (size_t)(col0 + sr1) * K + lc0;
    __bf16* lA0 = As + w * 512;
    __bf16* lA1 = As + 2048 + w * 512;
    __bf16* lB0 = Bs + w * 512;
    __bf16* lB1 = Bs + 2048 + w * 512;

    int rca = ((g ^ ((l15 >> 1) & 3)) << 3); // swizzled read chunk

#pragma unroll
    for (int i = 0; i < 4; ++i)
#pragma unroll
        for (int j = 0; j < 4; ++j) acc[i][j] = f4zero();

    for (int k0 = 0; k0 < K; k0 += 32) {
        __syncthreads();
        GLOAD_LDS16(gA0 + k0, lA0);
        GLOAD_LDS16(gA1 + k0, lA1);
        GLOAD_LDS16(gB0 + k0, lB0);
        GLOAD_LDS16(gB1 + k0, lB1);
        __syncthreads();

        bf16x8 af[4], bfr[4];
#pragma unroll
        for (int i = 0; i < 4; ++i) af[i] = *(const bf16x8*)&As[(wr + i * 16 + l15) * 32 + rca];
#pragma unroll
        for (int j = 0; j < 4; ++j) bfr[j] = *(const bf16x8*)&Bs[(wc + j * 16 + l15) * 32 + rca];
        __builtin_amdgcn_s_setprio(1);
#pragma unroll
        for (int i = 0; i < 4; ++i)
#pragma unroll
            for (int j = 0; j < 4; ++j)
                acc[i][j] = __builtin_amdgcn_mfma_f32_16x16x32_bf16(af[i], bfr[j], acc[i][j], 0, 0, 0);
        __builtin_amdgcn_s_setprio(0);
    }
}

// Fused QKV GEMM, 1D grid of 768 blocks:
//  bid <  512: Q/K (z = bid>>8) with RoPE epilogue, C row-major [row][DIM]
//  bid >= 512: V computed TRANSPOSED: vt[b*1024 + n][s] = sum_k wtv[n][k]*xn_b[s][k]
__global__ __launch_bounds__(256) void gemm_qkv_kernel(const __bf16* __restrict__ xn,
                                                       const __bf16* __restrict__ wq,
                                                       const __bf16* __restrict__ wk,
                                                       const __bf16* __restrict__ wv,
                                                       __bf16* __restrict__ qo,
                                                       __bf16* __restrict__ ko,
                                                       __bf16* __restrict__ vt,
                                                       const float* __restrict__ cosT,
                                                       const float* __restrict__ sinT) {
    __shared__ __bf16 As[128 * 32];
    __shared__ __bf16 Bs[128 * 32];
    int bid = blockIdx.x;
    int tid = threadIdx.x;
    int w = tid >> 6, l = tid & 63, l15 = l & 15, g = l >> 4;
    int wr = (w >> 1) << 6, wc = (w & 1) << 6;
    f32x4 acc[4][4];

    if (bid < 512) {
        int z = bid >> 8, t = bid & 255;
        int col0 = (t & 7) << 7, row0 = (t >> 3) << 7;
        gemm_core(xn, z ? wk : wq, DIM, As, Bs, acc, row0, col0);
        __bf16* C = z ? ko : qo;
        int colbase = col0 + wc;
#pragma unroll
        for (int i = 0; i < 4; ++i) {
#pragma unroll
            for (int r = 0; r < 4; ++r) {
                int row = row0 + wr + i * 16 + g * 4 + r;
                int s = row & (SEQ - 1);
#pragma unroll
                for (int j = 0; j < 2; ++j) {
                    float c = cosT[s * 32 + j * 16 + l15];
                    float sn = sinT[s * 32 + j * 16 + l15];
                    float x1 = acc[i][j][r], x2 = acc[i][j + 2][r];
                    C[(size_t)row * DIM + colbase + j * 16 + l15] = (__bf16)(x1 * c - x2 * sn);
                    C[(size_t)row * DIM + colbase + (j + 2) * 16 + l15] = (__bf16)(x1 * sn + x2 * c);
                }
            }
        }
    } else {
        int t = bid - 512;           // 256 blocks: [batch 2][n-blocks 8][s-blocks 16]
        int b = t >> 7, r7 = t & 127;
        int row0 = (r7 >> 4) << 7;   // n
        int col0 = (r7 & 15) << 7;   // s
        gemm_core(wv, xn + (size_t)b * SEQ * DIM, DIM, As, Bs, acc, row0, col0);
        __bf16* C = vt + (size_t)b * (NHEADS * HD) * SEQ;
#pragma unroll
        for (int i = 0; i < 4; ++i)
#pragma unroll
            for (int j = 0; j < 4; ++j)
#pragma unroll
                for (int r = 0; r < 4; ++r) {
                    int row = row0 + wr + i * 16 + g * 4 + r;
                    int col = col0 + wc + j * 16 + l15;
                    C[(size_t)row * SEQ + col] = (__bf16)acc[i][j][r];
                }
    }
}

__global__ __launch_bounds__(256) void gemm_out_kernel(const __bf16* __restrict__ ctx,
                                                       const __bf16* __restrict__ wo,
                                                       float* __restrict__ out) {
    __shared__ __bf16 As[128 * 32];
    __shared__ __bf16 Bs[128 * 32];
    int row0 = (int)blockIdx.y << 7, col0 = (int)blockIdx.x << 7;
    f32x4 acc[4][4];
    gemm_core(ctx, wo, DIM, As, Bs, acc, row0, col0);
    int tid = threadIdx.x;
    int w = tid >> 6, l = tid & 63, l15 = l & 15, g = l >> 4;
    int wr = (w >> 1) << 6, wc = (w & 1) << 6;
#pragma unroll
    for (int i = 0; i < 4; ++i)
#pragma unroll
        for (int j = 0; j < 4; ++j)
#pragma unroll
            for (int r = 0; r < 4; ++r) {
                int row = row0 + wr + i * 16 + g * 4 + r;
                int col = col0 + wc + j * 16 + l15;
                out[(size_t)row * DIM + col] = acc[i][j][r];
            }
}

// ---------------- Split-KV causal flash attention (swapped-operand 32x32 MFMA) ----------------
// Grid: (32 bh, 80 chunk-slots). Block = 2 waves x 32 q-rows (64-row q-tile).
// Each chunk covers up to 8 KV tiles (512 positions); writes unnormalized partial
// (O bf16, m/l f32) to workspace. attn_combine merges chunks.
__global__ __launch_bounds__(128) void attn_mfma_kernel(const __bf16* __restrict__ q,
                                                        const __bf16* __restrict__ k,
                                                        const __bf16* __restrict__ vt,
                                                        __bf16* __restrict__ part_O,
                                                        float* __restrict__ part_ml) {
    int bh = blockIdx.x;
    int slot = 79 - (int)blockIdx.y; // heavy chunks dispatch first
    int qb, ci;
    if (slot < 8) { qb = slot; ci = 0; }
    else if (slot < 24) { int t = slot - 8; qb = 8 + (t >> 1); ci = t & 1; }
    else if (slot < 48) { int t = slot - 24; qb = 16 + t / 3; ci = t - 3 * (qb - 16); }
    else { int t = slot - 48; qb = 24 + (t >> 2); ci = t & 3; }
    int nch = (qb >> 3) + 1;
    int ntiles = (ci == nch - 1) ? (qb + 1 - (ci << 3)) : 8;
    int ks0 = ci << 9; // chunk KV start

    int b = bh >> 4, h = bh & 15;
    __shared__ __bf16 Ks[64][72]; // [s_local][d]
    __shared__ __bf16 Vs[64][72]; // [d][s_local]
    int tid = threadIdx.x, w = tid >> 6, l = tid & 63;
    int l31 = l & 31, hi = l >> 5;
    size_t hoff = (size_t)(b * SEQ) * DIM + h * HD;
    const __bf16* vth = vt + (size_t)bh * HD * SEQ;
    int qw0 = qb * 64 + w * 32;
    int qrow = qw0 + l31;

    // Q B-frags, pre-scaled by 0.125*log2(e) -> QK^T lands in exp2 domain
    bf16x8 qf[4];
    const float c2 = 0.125f * 1.44269504f;
#pragma unroll
    for (int g = 0; g < 4; ++g) {
        bf16x8 t0 = *(const bf16x8*)&q[hoff + (size_t)qrow * DIM + g * 16 + hi * 8];
#pragma unroll
        for (int e = 0; e < 8; ++e) qf[g][e] = (__bf16)((float)t0[e] * c2);
    }

    f32x16 oA, oB;
#pragma unroll
    for (int r = 0; r < 16; ++r) {
        oA[r] = 0.f;
        oB[r] = 0.f;
    }
    float m_run = -1e30f, l_run = 0.f;

    // staging: 128 threads, 4 chunks each of K and V^T (rows c*16+sr)
    int sr = tid >> 3, sc = (tid & 7) * 8;
    bf16x8 rk[4], rv[4];
#pragma unroll
    for (int c = 0; c < 4; ++c) {
        rk[c] = *(const bf16x8*)&k[hoff + (size_t)(ks0 + c * 16 + sr) * DIM + sc];
        rv[c] = *(const bf16x8*)&vth[(size_t)(c * 16 + sr) * SEQ + ks0 + sc];
    }

    for (int st = 0; st < ntiles; ++st) {
        int s0 = ks0 + (st << 6);
        __syncthreads();
#pragma unroll
        for (int c = 0; c < 4; ++c) {
            *(bf16x8*)&Ks[c * 16 + sr][sc] = rk[c];
            *(bf16x8*)&Vs[c * 16 + sr][sc] = rv[c];
        }
        __syncthreads();
        if (st + 1 < ntiles) {
            int sn = s0 + 64;
#pragma unroll
            for (int c = 0; c < 4; ++c) {
                rk[c] = *(const bf16x8*)&k[hoff + (size_t)(sn + c * 16 + sr) * DIM + sc];
                rv[c] = *(const bf16x8*)&vth[(size_t)(c * 16 + sr) * SEQ + sn + sc];
            }
        }

        // S^T = mfma(K, Q): sa = k-rows 0..31, sb = 32..63 (cols = q = lane&31)
        f32x16 sa, sb;
#pragma unroll
        for (int r = 0; r < 16; ++r) {
            sa[r] = 0.f;
            sb[r] = 0.f;
        }
        __builtin_amdgcn_s_setprio(1);
#pragma unroll
        for (int g = 0; g < 4; ++g) {
            bf16x8 ka = *(const bf16x8*)&Ks[l31][g * 16 + hi * 8];
            bf16x8 kb2 = *(const bf16x8*)&Ks[32 + l31][g * 16 + hi * 8];
            sa = __builtin_amdgcn_mfma_f32_32x32x16_bf16(ka, qf[g], sa, 0, 0, 0);
            sb = __builtin_amdgcn_mfma_f32_32x32x16_bf16(kb2, qf[g], sb, 0, 0, 0);
        }
        __builtin_amdgcn_s_setprio(0);

        if (s0 + 63 > qw0) { // causal mask (diagonal tile only)
#pragma unroll
            for (int r = 0; r < 16; ++r) {
                int kg = s0 + (r & 3) + 8 * (r >> 2) + 4 * hi;
                if (kg > qrow) sa[r] = -1e30f;
                if (kg + 32 > qrow) sb[r] = -1e30f;
            }
        }

        // online softmax (exp2 domain), defer-max THR=10
        float lmax = -3e38f;
#pragma unroll
        for (int r = 0; r < 16; ++r) lmax = fmaxf(lmax, fmaxf(sa[r], sb[r]));
        if (!__all(lmax <= m_run + 10.0f)) {
            float omax = fmaxf(lmax, __shfl_xor(lmax, 32));
            float m_new = fmaxf(m_run, omax);
            float alpha = exp2f(m_run - m_new);
            l_run *= alpha;
#pragma unroll
            for (int r = 0; r < 16; ++r) {
                oA[r] *= alpha;
                oB[r] *= alpha;
            }
            m_run = m_new;
        }
        float ls = 0.f;
#pragma unroll
        for (int r = 0; r < 16; ++r) {
            sa[r] = exp2f(sa[r] - m_run);
            ls += sa[r];
            sb[r] = exp2f(sb[r] - m_run);
            ls += sb[r];
        }
        l_run += ls + __shfl_xor(ls, 32);

        // pack P -> bf16 B-frags: pa[ks] = P[q=lane&31][ks*16 + hi*8 + 0..7]
        bf16x8 pa[4];
#pragma unroll
        for (int g = 0; g < 2; ++g) {
            unsigned a_ = cvtpk(sa[8 * g + 0], sa[8 * g + 1]);
            unsigned b_ = cvtpk(sa[8 * g + 4], sa[8 * g + 5]);
            pl32swap(a_, b_);
            unsigned c_ = cvtpk(sa[8 * g + 2], sa[8 * g + 3]);
            unsigned d_ = cvtpk(sa[8 * g + 6], sa[8 * g + 7]);
            pl32swap(c_, d_);
            u32x4 t4 = {a_, c_, b_, d_};
            pa[g] = __builtin_bit_cast(bf16x8, t4);
        }
#pragma unroll
        for (int g = 0; g < 2; ++g) {
            unsigned a_ = cvtpk(sb[8 * g + 0], sb[8 * g + 1]);
            unsigned b_ = cvtpk(sb[8 * g + 4], sb[8 * g + 5]);
            pl32swap(a_, b_);
            unsigned c_ = cvtpk(sb[8 * g + 2], sb[8 * g + 3]);
            unsigned d_ = cvtpk(sb[8 * g + 6], sb[8 * g + 7]);
            pl32swap(c_, d_);
            u32x4 t4 = {a_, c_, b_, d_};
            pa[2 + g] = __builtin_bit_cast(bf16x8, t4);
        }

        // O^T += mfma(V^T, P): oA = d 0..31, oB = d 32..63 (cols = q = lane&31)
        __builtin_amdgcn_s_setprio(1);
#pragma unroll
        for (int ks = 0; ks < 4; ++ks) {
            bf16x8 va = *(const bf16x8*)&Vs[l31][ks * 16 + hi * 8];
            bf16x8 vb2 = *(const bf16x8*)&Vs[32 + l31][ks * 16 + hi * 8];
            oA = __builtin_amdgcn_mfma_f32_32x32x16_bf16(va, pa[ks], oA, 0, 0, 0);
            oB = __builtin_amdgcn_mfma_f32_32x32x16_bf16(vb2, pa[ks], oB, 0, 0, 0);
        }
        __builtin_amdgcn_s_setprio(0);
    }

    // write unnormalized partial: O as bf16, m/l as f32
    int gslot = bh * 80 + slot;
    int qloc = w * 32 + l31;
    __bf16* po = part_O + (size_t)gslot * 4096 + qloc * 64;
#pragma unroll
    for (int rr = 0; rr < 16; rr += 4) {
        int d0 = 8 * (rr >> 2) + 4 * hi;
        uint2 pA = {cvtpk(oA[rr], oA[rr + 1]), cvtpk(oA[rr + 2], oA[rr + 3])};
        uint2 pB = {cvtpk(oB[rr], oB[rr + 1]), cvtpk(oB[rr + 2], oB[rr + 3])};
        *(uint2*)&po[d0] = pA;
        *(uint2*)&po[32 + d0] = pB;
    }
    if (hi == 0) {
        part_ml[(size_t)gslot * 128 + qloc] = m_run;
        part_ml[(size_t)gslot * 128 + 64 + qloc] = l_run;
    }
}

// ---------------- Combine split-KV partials -> ctx ----------------
// Grid (32 bh, 32 qb), 256 threads: thread owns (row = t>>2, 16-d segment).
__global__ __launch_bounds__(256) void attn_combine_kernel(const __bf16* __restrict__ part_O,
                                                           const float* __restrict__ part_ml,
                                                           __bf16* __restrict__ ctx) {
    int bh = blockIdx.x, qb = blockIdx.y;
    int b = bh >> 4, h = bh & 15;
    int nch = (qb >> 3) + 1;
    int base = slot_base(qb);
    size_t so = (size_t)bh * 80 + base;
    int t = threadIdx.x;
    int row = t >> 2, dseg = (t & 3) << 4;

    float mv0 = -1e30f, mv1 = -1e30f, mv2 = -1e30f, mv3 = -1e30f;
    mv0 = part_ml[(so + 0) * 128 + row];
    if (nch > 1) mv1 = part_ml[(so + 1) * 128 + row];
    if (nch > 2) mv2 = part_ml[(so + 2) * 128 + row];
    if (nch > 3) mv3 = part_ml[(so + 3) * 128 + row];
    float mmax = fmaxf(fmaxf(mv0, mv1), fmaxf(mv2, mv3));

    float acc[16];
#pragma unroll
    for (int e = 0; e < 16; ++e) acc[e] = 0.f;
    float lsum = 0.f;

#pragma unroll 4
    for (int i = 0; i < 4; ++i) {
        if (i >= nch) break;
        float mi = i == 0 ? mv0 : i == 1 ? mv1 : i == 2 ? mv2 : mv3;
        float wsc = exp2f(mi - mmax);
        lsum += wsc * part_ml[(so + i) * 128 + 64 + row];
        const __bf16* po = part_O + (so + i) * 4096 + row * 64 + dseg;
        bf16x8 a = *(const bf16x8*)po;
        bf16x8 b2 = *(const bf16x8*)(po + 8);
#pragma unroll
        for (int e = 0; e < 8; ++e) {
            acc[e] += wsc * (float)a[e];
            acc[8 + e] += wsc * (float)b2[e];
        }
    }

    float inv = 1.0f / lsum;
    bf16x8 oa, ob;
#pragma unroll
    for (int e = 0; e < 8; ++e) {
        oa[e] = (__bf16)(acc[e] * inv);
        ob[e] = (__bf16)(acc[8 + e] * inv);
    }
    size_t off = ((size_t)(b * SEQ) + qb * 64 + row) * DIM + h * HD + dseg;
    *(bf16x8*)&ctx[off] = oa;
    *(bf16x8*)&ctx[off + 8] = ob;
}

extern "C" void kernel_launch(void* const* d_in, const int* in_sizes, int n_in,
                              void* d_out, int out_size, void* d_ws, size_t ws_size,
                              hipStream_t stream) {
    const float* x = (const float*)d_in[0];
    const float* w_norm = (const float*)d_in[1];
    const float* Wq = (const float*)d_in[2];
    const float* Wk = (const float*)d_in[3];
    const float* Wv = (const float*)d_in[4];
    const float* Wo = (const float*)d_in[5];
    float* out = (float*)d_out;
    char* w8 = (char*)d_ws;

    const size_t MB = 1ull << 20;
    // phase 1 region [0,14MB): xn + Wq/Wk/Wv transposed weights (dead after QKV GEMM)
    __bf16* xn = (__bf16*)(w8);               // [0,8)
    __bf16* wtq = (__bf16*)(w8 + 8 * MB);     // [8,10)
    __bf16* wtk = (__bf16*)(w8 + 10 * MB);    // [10,12)
    __bf16* wtv = (__bf16*)(w8 + 12 * MB);    // [12,14)
    // part_O reuses [0,20MB) during attention
    __bf16* part_O = (__bf16*)(w8);           // 2560 slots * 8KB = 20MB
    __bf16* wto = (__bf16*)(w8 + 20 * MB);    // [20,22)
    __bf16* qb = (__bf16*)(w8 + 22 * MB);     // [22,30)
    __bf16* kb = (__bf16*)(w8 + 30 * MB);     // [30,38)
    __bf16* vtb = (__bf16*)(w8 + 38 * MB);    // [38,46)
    __bf16* ctx = (__bf16*)(w8 + 46 * MB);    // [46,54)
    float* cosT = (float*)(w8 + 54 * MB);     // 256KB
    float* sinT = cosT + SEQ * 32;            // 256KB -> ends 54.5MB
    float* part_ml = (float*)(w8 + 55 * MB);  // 2560*512B = 1.25MB -> ends 56.25MB

    wcvt_kernel<<<dim3(32, 32, 4), 256, 0, stream>>>(Wq, Wk, Wv, Wo, wtq, wtk, wtv, wto);
    rmsnorm_bf16<<<ROWS, 256, 0, stream>>>(x, w_norm, xn);
    rope_table_kernel<<<(SEQ * 32) / 256, 256, 0, stream>>>(cosT, sinT);

    gemm_qkv_kernel<<<768, 256, 0, stream>>>(xn, wtq, wtk, wtv, qb, kb, vtb, cosT, sinT);

    attn_mfma_kernel<<<dim3(BATCH * NHEADS, 80), 128, 0, stream>>>(qb, kb, vtb, part_O, part_ml);
    attn_combine_kernel<<<dim3(BATCH * NHEADS, SEQ / 64), 256, 0, stream>>>(part_O, part_ml, ctx);

    gemm_out_kernel<<<dim3(DIM / 128, ROWS / 128), 256, 0, stream>>>(ctx, wto, out);
}